// Round 7
// baseline (787.745 us; speedup 1.0000x reference)
//
#include <hip/hip_runtime.h>
#include <hip/hip_bf16.h>

// ---------------------------------------------------------------------------
// LSTM_net: 6x biLSTM(H=8, T=4) + composed affine head, B=131072. All f32.
// Round 7: Z-hoisting. Per layer-dir: precompute Z[t][g] = b + Wi·x(t) for all
// 4 timesteps into registers (independent, latency-tolerant), then the serial
// recurrence is only gate = Z + Wh·h (4 pk_fma per gate). Only Wh (36 regs)
// needs residency; Wi reloads (if any) pipeline freely in the Z phase.
// h-propagation via LDS store+readback (round-6, 0 conflicts). E=2 elems/lane.
// block=256 (4 waves, 64 elems); __launch_bounds__(256,4) -> <=128 VGPR,
// 4 waves/SIMD to match the LDS occupancy cap.
// ---------------------------------------------------------------------------

using f32x2 = __attribute__((ext_vector_type(2))) float;
using f32x4 = __attribute__((ext_vector_type(4))) float;

#define OFF_WIH0 0      // [2][32][2]   = 128
#define OFF_WHH0 128    // [2][32][8]   = 512
#define OFF_B0   640    // [2][32]      = 64   (b_ih0 + b_hh0)
#define OFF_WIH  704    // [5][2][32][16] = 5120
#define OFF_WHH  5824   // [5][2][32][8]  = 2560
#define OFF_B    8384   // [5][2][32]     = 640 (b_ih + b_hh)
#define OFF_M    9024   // [16][64]       = 1024 (composed conv head, linear)
#define OFF_MB   10048  // [16]           = 16   (composed conv head, bias)

__device__ __forceinline__ float rcpf_(float x) {
#if __has_builtin(__builtin_amdgcn_rcpf)
    return __builtin_amdgcn_rcpf(x);
#else
    return 1.0f / x;
#endif
}
__device__ __forceinline__ float exp2f_(float x) {
#if __has_builtin(__builtin_amdgcn_exp2f)
    return __builtin_amdgcn_exp2f(x);
#else
    return exp2f(x);
#endif
}
__device__ __forceinline__ float sigm(float x) {
    return rcpf_(1.0f + exp2f_(-1.44269504f * x));
}
__device__ __forceinline__ float tanhx(float x) {
    return fmaf(2.0f, rcpf_(1.0f + exp2f_(-2.88539008f * x)), -1.0f);
}

// ---------------------------------------------------------------------------
// prep (fused): blocks 0..35 repack LSTM weights; blocks 36..40 compose the
// affine conv/deconv/fc head into M[16x64] + Mb[16].  (verified rounds 2-6)
// ---------------------------------------------------------------------------
__global__ __launch_bounds__(256) void prep_all(
    const float* __restrict__ wih0, const float* __restrict__ whh0,
    const float* __restrict__ bih0, const float* __restrict__ bhh0,
    const float* __restrict__ wih,  const float* __restrict__ whh,
    const float* __restrict__ bih,  const float* __restrict__ bhh,
    const float* __restrict__ c1w, const float* __restrict__ c1b,
    const float* __restrict__ c2w, const float* __restrict__ c2b,
    const float* __restrict__ d1w, const float* __restrict__ d1b,
    const float* __restrict__ d2w, const float* __restrict__ d2b,
    const float* __restrict__ f1w, const float* __restrict__ f1b,
    const float* __restrict__ f2w, const float* __restrict__ f2b,
    float* __restrict__ W)
{
    __shared__ float A[13][232];
    __shared__ float Bf[13][232];
    const int tid = threadIdx.x;

    if (blockIdx.x < 36) {
        int t = blockIdx.x * 256 + tid;
        const int n = 36 * 256;
        for (int i = t; i < 128; i += n)  W[OFF_WIH0 + i] = wih0[i];
        for (int i = t; i < 512; i += n)  W[OFF_WHH0 + i] = whh0[i];
        for (int i = t; i < 64; i += n)   W[OFF_B0 + i] = bih0[i] + bhh0[i];
        for (int i = t; i < 5120; i += n) W[OFF_WIH + i] = wih[i];
        for (int i = t; i < 2560; i += n) W[OFF_WHH + i] = whh[i];
        for (int i = t; i < 640; i += n)  W[OFF_B + i] = bih[i] + bhh[i];
        return;
    }
    const int base = (blockIdx.x - 36) * 13;

    for (int idx = tid; idx < 13 * 64; idx += 256) {
        int cl = idx / 64, r = idx % 64;
        A[cl][r] = (base + cl == r) ? 1.0f : 0.0f;
    }
    __syncthreads();
    for (int idx = tid; idx < 13 * 120; idx += 256) {
        int cl = idx / 120, rr = idx % 120; int o = rr / 15, l = rr % 15;
        float acc = (base + cl == 64) ? c1b[o] : 0.0f;
        for (int i = 0; i < 4; i++)
            for (int kk = 0; kk < 2; kk++)
                acc += c1w[(o * 4 + i) * 2 + kk] * A[cl][i * 16 + l + kk];
        Bf[cl][rr] = acc;
    }
    __syncthreads();
    for (int idx = tid; idx < 13 * 224; idx += 256) {
        int cl = idx / 224, rr = idx % 224; int o = rr / 14, l = rr % 14;
        float acc = (base + cl == 64) ? c2b[o] : 0.0f;
        for (int i = 0; i < 8; i++)
            for (int kk = 0; kk < 2; kk++)
                acc += c2w[(o * 8 + i) * 2 + kk] * Bf[cl][i * 15 + l + kk];
        A[cl][rr] = acc;
    }
    __syncthreads();
    for (int idx = tid; idx < 13 * 120; idx += 256) {
        int cl = idx / 120, rr = idx % 120; int o = rr / 15, l = rr % 15;
        float acc = (base + cl == 64) ? d1b[o] : 0.0f;
        for (int i = 0; i < 16; i++)
            for (int kk = 0; kk < 2; kk++) {
                int ls = l - kk;
                if (ls >= 0 && ls < 14)
                    acc += d1w[(i * 8 + o) * 2 + kk] * A[cl][i * 14 + ls];
            }
        Bf[cl][rr] = acc;
    }
    __syncthreads();
    for (int idx = tid; idx < 13 * 64; idx += 256) {
        int cl = idx / 64, rr = idx % 64; int o = rr / 16, l = rr % 16;
        float acc = (base + cl == 64) ? d2b[o] : 0.0f;
        for (int i = 0; i < 8; i++)
            for (int kk = 0; kk < 2; kk++) {
                int ls = l - kk;
                if (ls >= 0 && ls < 15)
                    acc += d2w[(i * 4 + o) * 2 + kk] * Bf[cl][i * 15 + ls];
            }
        A[cl][rr] = acc;
    }
    __syncthreads();
    for (int idx = tid; idx < 13 * 32; idx += 256) {
        int cl = idx / 32, rr = idx % 32; int ch = rr / 8, jj = rr % 8;
        float acc = (base + cl == 64) ? f1b[jj] : 0.0f;
        for (int l = 0; l < 16; l++)
            acc += f1w[jj * 16 + l] * A[cl][ch * 16 + l];
        Bf[cl][rr] = acc;
    }
    __syncthreads();
    for (int idx = tid; idx < 13 * 16; idx += 256) {
        int cl = idx / 16, rr = idx % 16; int ch = rr / 4, m = rr % 4;
        int col = base + cl;
        if (col > 64) continue;
        float acc = (col == 64) ? f2b[m] : 0.0f;
        for (int j = 0; j < 8; j++)
            acc += f2w[m * 8 + j] * Bf[cl][ch * 8 + j];
        if (col < 64) W[OFF_M + rr * 64 + col] = acc;
        else          W[OFF_MB + rr] = acc;
    }
}

// ---------------------------------------------------------------------------
// one layer-direction, Din=16, E=2 elems per lane, Z-hoisted.
// ---------------------------------------------------------------------------
template<bool FWD, bool LAST>
__device__ __forceinline__ void layer16(
    const float* __restrict__ Wi, const float* __restrict__ Wh,
    const float* __restrict__ Bs,
    const float* __restrict__ h0s, const float* __restrict__ c0s,
    int gelem0, int u,
    float* const (&lin)[2], float* const (&lout)[2])
{
    // ---- Z phase: Z[e][t][g] = b[g] + Wi[g,:] . x_t  (independent work) ----
    f32x4 wiv[4][4];
    f32x4 bsv;
#pragma unroll
    for (int g = 0; g < 4; g++) {
        const int r = u + 8 * g;
        const f32x4* wr = reinterpret_cast<const f32x4*>(Wi + r * 16);
        wiv[g][0] = wr[0]; wiv[g][1] = wr[1]; wiv[g][2] = wr[2]; wiv[g][3] = wr[3];
        bsv[g] = Bs[r];
    }
    float z[2][4][4];
#pragma unroll
    for (int e = 0; e < 2; e++) {
#pragma unroll
        for (int t = 0; t < 4; t++) {
            const f32x4* ip = reinterpret_cast<const f32x4*>(lin[e] + 16 * t);
            f32x4 i0 = ip[0], i1 = ip[1], i2 = ip[2], i3 = ip[3];
            f32x2 xin[8];
            xin[0] = f32x2{i0.x, i0.y}; xin[1] = f32x2{i0.z, i0.w};
            xin[2] = f32x2{i1.x, i1.y}; xin[3] = f32x2{i1.z, i1.w};
            xin[4] = f32x2{i2.x, i2.y}; xin[5] = f32x2{i2.z, i2.w};
            xin[6] = f32x2{i3.x, i3.y}; xin[7] = f32x2{i3.z, i3.w};
#pragma unroll
            for (int g = 0; g < 4; g++) {
                f32x2 a = f32x2{bsv[g], 0.0f};
#pragma unroll
                for (int j = 0; j < 4; j++) {
                    f32x2 wlo = f32x2{wiv[g][j].x, wiv[g][j].y};
                    f32x2 whi = f32x2{wiv[g][j].z, wiv[g][j].w};
                    a = __builtin_elementwise_fma(xin[2 * j], wlo, a);
                    a = __builtin_elementwise_fma(xin[2 * j + 1], whi, a);
                }
                z[e][t][g] = a.x + a.y;
            }
        }
    }

    // ---- R phase: serial recurrence, only Wh·h per gate (4 pk_fma) ----
    f32x4 whv[4][2];
#pragma unroll
    for (int g = 0; g < 4; g++) {
        const f32x4* ur = reinterpret_cast<const f32x4*>(Wh + (u + 8 * g) * 8);
        whv[g][0] = ur[0]; whv[g][1] = ur[1];
    }
    f32x4 hg[2][2];
    float cc[2];
#pragma unroll
    for (int e = 0; e < 2; e++) {
        const f32x4* hp = reinterpret_cast<const f32x4*>(h0s + (size_t)(gelem0 + e) * 8);
        hg[e][0] = hp[0]; hg[e][1] = hp[1];
        cc[e] = c0s[(size_t)(gelem0 + e) * 8 + u];
    }
    float hreg[2][4];
    const int off = FWD ? 0 : 8;

#pragma unroll
    for (int s = 0; s < 4; s++) {
        const int t = FWD ? s : 3 - s;
        const int tprev = FWD ? t - 1 : t + 1;
#pragma unroll
        for (int e = 0; e < 2; e++) {
            f32x4 ha, hb;
            if (s == 0) { ha = hg[e][0]; hb = hg[e][1]; }
            else {
                const f32x4* hp = reinterpret_cast<const f32x4*>(lout[e] + 16 * tprev + off);
                ha = hp[0]; hb = hp[1];
            }
            f32x2 hx[4];
            hx[0] = f32x2{ha.x, ha.y}; hx[1] = f32x2{ha.z, ha.w};
            hx[2] = f32x2{hb.x, hb.y}; hx[3] = f32x2{hb.z, hb.w};
            float gate[4];
#pragma unroll
            for (int g = 0; g < 4; g++) {
                f32x2 a = f32x2{z[e][t][g], 0.0f};
                f32x2 wlo0 = f32x2{whv[g][0].x, whv[g][0].y};
                f32x2 whi0 = f32x2{whv[g][0].z, whv[g][0].w};
                f32x2 wlo1 = f32x2{whv[g][1].x, whv[g][1].y};
                f32x2 whi1 = f32x2{whv[g][1].z, whv[g][1].w};
                a = __builtin_elementwise_fma(hx[0], wlo0, a);
                a = __builtin_elementwise_fma(hx[1], whi0, a);
                a = __builtin_elementwise_fma(hx[2], wlo1, a);
                a = __builtin_elementwise_fma(hx[3], whi1, a);
                gate[g] = a.x + a.y;
            }
            float si = sigm(gate[0]);
            float sf = sigm(gate[1]);
            float tg = tanhx(gate[2]);
            float so = sigm(gate[3]);
            cc[e] = fmaf(sf, cc[e], si * tg);
            float hn = so * tanhx(cc[e]);
            lout[e][16 * t + off + u] = hn;
            if (LAST) hreg[e][s] = hn;
        }
    }
    if (LAST) {
#pragma unroll
        for (int e = 0; e < 2; e++)
#pragma unroll
            for (int s = 0; s < 4; s++) {
                const int t = FWD ? s : 3 - s;
                lout[e][16 * t + off + u] = sigm(hreg[e][s]);
            }
    }
}

// layer 0 (Din=2): Z trivial from register inputs
template<bool FWD>
__device__ __forceinline__ void layer2(
    const float* __restrict__ Wi, const float* __restrict__ Wh,
    const float* __restrict__ Bs,
    const float* __restrict__ h0s, const float* __restrict__ c0s,
    int gelem0, int u,
    const f32x2 (&xin2)[2][4], float* const (&lout)[2])
{
    f32x2 wiv[4];
    f32x4 bsv;
#pragma unroll
    for (int g = 0; g < 4; g++) {
        const int r = u + 8 * g;
        wiv[g] = *reinterpret_cast<const f32x2*>(Wi + r * 2);
        bsv[g] = Bs[r];
    }
    float z[2][4][4];
#pragma unroll
    for (int e = 0; e < 2; e++)
#pragma unroll
        for (int t = 0; t < 4; t++)
#pragma unroll
            for (int g = 0; g < 4; g++)
                z[e][t][g] = fmaf(xin2[e][t].x, wiv[g].x,
                             fmaf(xin2[e][t].y, wiv[g].y, bsv[g]));

    f32x4 whv[4][2];
#pragma unroll
    for (int g = 0; g < 4; g++) {
        const f32x4* ur = reinterpret_cast<const f32x4*>(Wh + (u + 8 * g) * 8);
        whv[g][0] = ur[0]; whv[g][1] = ur[1];
    }
    f32x4 hg[2][2];
    float cc[2];
#pragma unroll
    for (int e = 0; e < 2; e++) {
        const f32x4* hp = reinterpret_cast<const f32x4*>(h0s + (size_t)(gelem0 + e) * 8);
        hg[e][0] = hp[0]; hg[e][1] = hp[1];
        cc[e] = c0s[(size_t)(gelem0 + e) * 8 + u];
    }
    const int off = FWD ? 0 : 8;

#pragma unroll
    for (int s = 0; s < 4; s++) {
        const int t = FWD ? s : 3 - s;
        const int tprev = FWD ? t - 1 : t + 1;
#pragma unroll
        for (int e = 0; e < 2; e++) {
            f32x4 ha, hb;
            if (s == 0) { ha = hg[e][0]; hb = hg[e][1]; }
            else {
                const f32x4* hp = reinterpret_cast<const f32x4*>(lout[e] + 16 * tprev + off);
                ha = hp[0]; hb = hp[1];
            }
            f32x2 hx[4];
            hx[0] = f32x2{ha.x, ha.y}; hx[1] = f32x2{ha.z, ha.w};
            hx[2] = f32x2{hb.x, hb.y}; hx[3] = f32x2{hb.z, hb.w};
            float gate[4];
#pragma unroll
            for (int g = 0; g < 4; g++) {
                f32x2 a = f32x2{z[e][t][g], 0.0f};
                f32x2 wlo0 = f32x2{whv[g][0].x, whv[g][0].y};
                f32x2 whi0 = f32x2{whv[g][0].z, whv[g][0].w};
                f32x2 wlo1 = f32x2{whv[g][1].x, whv[g][1].y};
                f32x2 whi1 = f32x2{whv[g][1].z, whv[g][1].w};
                a = __builtin_elementwise_fma(hx[0], wlo0, a);
                a = __builtin_elementwise_fma(hx[1], whi0, a);
                a = __builtin_elementwise_fma(hx[2], wlo1, a);
                a = __builtin_elementwise_fma(hx[3], whi1, a);
                gate[g] = a.x + a.y;
            }
            float si = sigm(gate[0]);
            float sf = sigm(gate[1]);
            float tg = tanhx(gate[2]);
            float so = sigm(gate[3]);
            cc[e] = fmaf(sf, cc[e], si * tg);
            lout[e][16 * t + off + u] = so * tanhx(cc[e]);
        }
    }
}

// ---------------------------------------------------------------------------
// main: block = 256 threads = 4 waves = 64 elems; 8 lanes x E=2 per slot
// ---------------------------------------------------------------------------
__global__ __launch_bounds__(256, 4) void lstm_main(
    const float* __restrict__ x, const float* __restrict__ h0,
    const float* __restrict__ c0, const float* __restrict__ W,
    float* __restrict__ out, int B)
{
    __shared__ float yb[2][64 * 68];   // ping-pong activations, stride 68
    const int tid = threadIdx.x;
    const int u = tid & 7;
    const int slot = tid >> 3;
    const int row0 = slot * 2;
    const int gelem0 = blockIdx.x * 64 + row0;

    float* y0[2]; float* y1[2];
#pragma unroll
    for (int e = 0; e < 2; e++) {
        y0[e] = &yb[0][(row0 + e) * 68];
        y1[e] = &yb[1][(row0 + e) * 68];
    }

    f32x2 xin2[2][4];
#pragma unroll
    for (int e = 0; e < 2; e++) {
        const f32x4* xp = reinterpret_cast<const f32x4*>(x + (size_t)(gelem0 + e) * 8);
        f32x4 a = xp[0], b = xp[1];
        xin2[e][0] = f32x2{a.x, a.y}; xin2[e][1] = f32x2{a.z, a.w};
        xin2[e][2] = f32x2{b.x, b.y}; xin2[e][3] = f32x2{b.z, b.w};
    }

    // layer 0 -> y0
    layer2<true>(W + OFF_WIH0, W + OFF_WHH0, W + OFF_B0,
                 h0 + (size_t)0 * B * 8, c0 + (size_t)0 * B * 8,
                 gelem0, u, xin2, y0);
    layer2<false>(W + OFF_WIH0 + 64, W + OFF_WHH0 + 256, W + OFF_B0 + 32,
                  h0 + (size_t)1 * B * 8, c0 + (size_t)1 * B * 8,
                  gelem0, u, xin2, y0);

    // layers 1..4: ping-pong; layer 5 writes sigm() into y1 for the head
#pragma unroll
    for (int l = 1; l <= 4; l++) {
        float* const (&lin)[2] = (l & 1) ? y0 : y1;
        float* const (&lout)[2] = (l & 1) ? y1 : y0;
        const float* wi = W + OFF_WIH + (size_t)(l - 1) * 1024;
        const float* wh = W + OFF_WHH + (size_t)(l - 1) * 512;
        const float* bb = W + OFF_B + (size_t)(l - 1) * 64;
        const int si = 2 * l;
        layer16<true, false>(wi, wh, bb,
                             h0 + (size_t)si * B * 8, c0 + (size_t)si * B * 8,
                             gelem0, u, lin, lout);
        layer16<false, false>(wi + 512, wh + 256, bb + 32,
                              h0 + (size_t)(si + 1) * B * 8, c0 + (size_t)(si + 1) * B * 8,
                              gelem0, u, lin, lout);
    }
    {
        const float* wi = W + OFF_WIH + (size_t)4 * 1024;
        const float* wh = W + OFF_WHH + (size_t)4 * 512;
        const float* bb = W + OFF_B + (size_t)4 * 64;
        layer16<true, true>(wi, wh, bb,
                            h0 + (size_t)10 * B * 8, c0 + (size_t)10 * B * 8,
                            gelem0, u, y0, y1);
        layer16<false, true>(wi + 512, wh + 256, bb + 32,
                             h0 + (size_t)11 * B * 8, c0 + (size_t)11 * B * 8,
                             gelem0, u, y0, y1);
    }

    // head: y1 holds sigm(s[64]); lane computes output rows 2u, 2u+1
    {
        const int o0 = 2 * u, o1 = 2 * u + 1;
        const f32x4* M0 = reinterpret_cast<const f32x4*>(W + OFF_M + o0 * 64);
        const f32x4* M1 = reinterpret_cast<const f32x4*>(W + OFF_M + o1 * 64);
        const float b0 = W[OFF_MB + o0];
        const float b1 = W[OFF_MB + o1];
#pragma unroll
        for (int e = 0; e < 2; e++) {
            float a0 = b0, a1 = b1;
#pragma unroll
            for (int q = 0; q < 16; q++) {
                f32x4 sv = *reinterpret_cast<const f32x4*>(y1[e] + 4 * q);
                f32x4 m0 = M0[q], m1 = M1[q];
                a0 = fmaf(sv.x, m0.x, a0); a0 = fmaf(sv.y, m0.y, a0);
                a0 = fmaf(sv.z, m0.z, a0); a0 = fmaf(sv.w, m0.w, a0);
                a1 = fmaf(sv.x, m1.x, a1); a1 = fmaf(sv.y, m1.y, a1);
                a1 = fmaf(sv.z, m1.z, a1); a1 = fmaf(sv.w, m1.w, a1);
            }
            f32x2 res;
            res.x = tanhx(a0);
            res.y = tanhx(a1);
            *reinterpret_cast<f32x2*>(out + (size_t)(gelem0 + e) * 16 + 2 * u) = res;
        }
    }
}

extern "C" void kernel_launch(void* const* d_in, const int* in_sizes, int n_in,
                              void* d_out, int out_size, void* d_ws, size_t ws_size,
                              hipStream_t stream)
{
    const float* x    = (const float*)d_in[0];
    const float* h0   = (const float*)d_in[1];
    const float* c0   = (const float*)d_in[2];
    const float* wih0 = (const float*)d_in[3];
    const float* whh0 = (const float*)d_in[4];
    const float* bih0 = (const float*)d_in[5];
    const float* bhh0 = (const float*)d_in[6];
    const float* wih  = (const float*)d_in[7];
    const float* whh  = (const float*)d_in[8];
    const float* bih  = (const float*)d_in[9];
    const float* bhh  = (const float*)d_in[10];
    const float* c1w  = (const float*)d_in[11];
    const float* c1b  = (const float*)d_in[12];
    const float* c2w  = (const float*)d_in[13];
    const float* c2b  = (const float*)d_in[14];
    const float* d1w  = (const float*)d_in[15];
    const float* d1b  = (const float*)d_in[16];
    const float* d2w  = (const float*)d_in[17];
    const float* d2b  = (const float*)d_in[18];
    const float* f1w  = (const float*)d_in[19];
    const float* f1b  = (const float*)d_in[20];
    const float* f2w  = (const float*)d_in[21];
    const float* f2b  = (const float*)d_in[22];

    float* W = (float*)d_ws;
    const int B = in_sizes[0] / 8;

    prep_all<<<41, 256, 0, stream>>>(wih0, whh0, bih0, bhh0, wih, whh, bih, bhh,
                                     c1w, c1b, c2w, c2b, d1w, d1b, d2w, d2b,
                                     f1w, f1b, f2w, f2b, W);
    lstm_main<<<B / 64, 256, 0, stream>>>(x, h0, c0, W, (float*)d_out, B);
}